// Round 15
// baseline (7411.185 us; speedup 1.0000x reference)
//
#include <hip/hip_runtime.h>

// ---------------------------------------------------------------------------
// Persistent 2-layer GRU, MI355X (gfx950).  B=128, T=1024, D=H=512.
// R14-proven structure (256 wgs x 256 thr, (layer, mtile, ntile) = 16 rows x
// 32 cols, k-split 4x128, weights in registers, 1-TERM bf16 h exchange via
// agent-scope MALL ops, per-wg seq words, vmcnt(0)-only waits, poll probe).
// CHANGE vs R14: LAYER-DECOUPLED BARRIERS + 3-buffer h0 rotation.
//   - h0 has 3 buffers: L0 writes h0[s%3] at interval s; readers use
//     h0[(s+2)%3]. Overwrite of h0[s%3] conflicts only with reads at
//     intervals == s+1 (mod 3), most recently s-2 -> protected by L0's
//     relaxed poll (L1 >= s  <=>  L1 finished s-1).
//   - L0 wgs poll: L0 peers >= s+1 (data dep), L1 peers >= s (overwrite
//     ack, one interval of slack) -> L0 runs ~1 interval ahead.
//   - L1 wgs poll: all >= s+1; the L0 half is instantly satisfied (L0 is
//     ahead), so L1 effectively waits only on its own 16 peers.
//   - h1 keeps R14's strict 2-buffer L1-only scheme (unchanged semantics).
// h loads use sc0 sc1 (L1+L2 bypass; R8 measured identical perf) so
// freshness never depends on L1 eviction.
// ---------------------------------------------------------------------------

#define TS   1024
#define HID  512
#define NWG  256
#define WGT  256

typedef __attribute__((ext_vector_type(8))) short bf16x8;
typedef __attribute__((ext_vector_type(4))) unsigned short u16x4;
typedef __attribute__((ext_vector_type(4))) float f32x4;

#define WS_FIN      2048
#define WS_HBUF     8192
#define HBUF_ELEMS  65536                             // 128*512 bf16 per buffer
#define WS_H1F      (WS_HBUF + 8 * HBUF_ELEMS * 2)    // fp32 [128][512]
#define WS_ZERO     (WS_HBUF + 8 * HBUF_ELEMS * 2)

__device__ __forceinline__ unsigned short f2bf(float f) {
    unsigned u = __float_as_uint(f);
    u += 0x7FFFu + ((u >> 16) & 1u);
    return (unsigned short)(u >> 16);
}
__device__ __forceinline__ float bf2f(unsigned short s) {
    return __uint_as_float(((unsigned)s) << 16);
}
__device__ __forceinline__ float sigm(float v) { return 1.0f / (1.0f + __expf(-v)); }
__device__ __forceinline__ float tanh_(float v) { return 1.0f - 2.0f / (1.0f + __expf(2.0f * v)); }

// agent-scope (MALL) ops
__device__ __forceinline__ void st_agent8(void* p, unsigned long long v) {
    asm volatile("global_store_dwordx2 %0, %1, off sc1" :: "v"(p), "v"(v) : "memory");
}
__device__ __forceinline__ void st_agent16(void* p, f32x4 v) {
    asm volatile("global_store_dwordx4 %0, %1, off sc1" :: "v"(p), "v"(v) : "memory");
}
__device__ __forceinline__ void ld_agent16_issue(bf16x8& d, const unsigned short* p) {
    asm volatile("global_load_dwordx4 %0, %1, off sc0 sc1" : "=v"(d) : "v"(p));
}
// plain cached load (x input), issue-only
__device__ __forceinline__ void ld16_issue(f32x4& d, const float* p) {
    asm volatile("global_load_dwordx4 %0, %1, off" : "=v"(d) : "v"(p));
}
__device__ __forceinline__ void wait_vm0() {
    asm volatile("s_waitcnt vmcnt(0)" ::: "memory");
    __builtin_amdgcn_sched_barrier(0);
}
// coherent fp32x4 load (FC epilogue only)
__device__ __forceinline__ f32x4 ld_coh16f(const float* p) {
    const unsigned long long* q = (const unsigned long long*)p;
    union { unsigned long long u[2]; f32x4 v; } r;
    r.u[0] = __hip_atomic_load(q,     __ATOMIC_RELAXED, __HIP_MEMORY_SCOPE_AGENT);
    r.u[1] = __hip_atomic_load(q + 1, __ATOMIC_RELAXED, __HIP_MEMORY_SCOPE_AGENT);
    return r.v;
}
__device__ __forceinline__ void splitPack2(float a, float b, unsigned& hiw, unsigned& low) {
    unsigned ba = __float_as_uint(a), bb = __float_as_uint(b);
    unsigned ha = ba & 0xFFFF0000u,   hb = bb & 0xFFFF0000u;
    float la = a - __uint_as_float(ha);
    float lb = b - __uint_as_float(hb);
    hiw = (ba >> 16) | hb;
    low = (__float_as_uint(la) >> 16) | (__float_as_uint(lb) & 0xFFFF0000u);
}

__global__ void __launch_bounds__(WGT, 1)
gru_persistent(const float* __restrict__ x,
               const float* __restrict__ wi0, const float* __restrict__ wh0,
               const float* __restrict__ bi0, const float* __restrict__ bh0,
               const float* __restrict__ wi1, const float* __restrict__ wh1,
               const float* __restrict__ bi1, const float* __restrict__ bh1,
               const float* __restrict__ fcw, const float* __restrict__ fcb,
               float* __restrict__ out, unsigned char* __restrict__ ws)
{
    __shared__ float ldsRed[3][64][49];        // 37632 B k-split partials

    const int tid   = threadIdx.x;
    const int lane  = tid & 63;
    const int kq    = tid >> 6;                // wave id = k-quarter
    const int wgid  = blockIdx.x;
    const int layer = wgid >> 7;
    const int wid   = wgid & 127;
    const int mtile = wid & 7;                 // 16-row m-tile (barrier group)
    const int ntile = wid >> 3;                // 32-col hidden tile (0..15)
    const int l15   = lane & 15;
    const int l4    = lane >> 4;
    const int gidx  = layer * 16 + ntile;      // 0..31 within mtile-group

    unsigned* seqA = (unsigned*)(ws + (size_t)mtile * 256);
    unsigned* fin  = (unsigned*)(ws + WS_FIN);
    unsigned short* hbm = (unsigned short*)(ws + WS_HBUF);
    float* h1f = (float*)(ws + WS_H1F);

    // h0: 3-buffer rotation (slots 0,1,2). h1: strict 2-buffer (slots 4,5).
    unsigned short* h0hi[3] = { hbm + 0 * HBUF_ELEMS, hbm + 1 * HBUF_ELEMS,
                                hbm + 2 * HBUF_ELEMS };
    unsigned short* h1hi[2] = { hbm + 4 * HBUF_ELEMS, hbm + 5 * HBUF_ELEMS };

    // ---- stage weight fragments into REGISTERS (fp32 -> bf16) ----
    bf16x8 wiR[4][6], whR[4][6];
    {
        const float* Wi = layer ? wi1 : wi0;
        const float* Wh = layer ? wh1 : wh0;
        #pragma unroll
        for (int kk = 0; kk < 4; ++kk) {
            const int kc = (kq << 2) + kk;
            #pragma unroll
            for (int f = 0; f < 6; ++f) {
                const int g = f >> 1, n2 = f & 1;
                const int jg = g * HID + ntile * 32 + n2 * 16 + l15;
                const float* pi = Wi + (size_t)jg * HID + kc * 32 + (l4 << 3);
                const float* ph = Wh + (size_t)jg * HID + kc * 32 + (l4 << 3);
                #pragma unroll
                for (int e = 0; e < 8; ++e) {
                    wiR[kk][f][e] = (short)f2bf(pi[e]);
                    whR[kk][f][e] = (short)f2bf(ph[e]);
                }
            }
        }
    }

    // ---- per-thread biases (wave 0 only) ----
    float br[2][4], bz[2][4], bni[2][4], bnh[2][4];
    if (kq == 0) {
        const float* Bi = layer ? bi1 : bi0;
        const float* Bh = layer ? bh1 : bh0;
        #pragma unroll
        for (int n2 = 0; n2 < 2; ++n2)
            #pragma unroll
            for (int r = 0; r < 4; ++r) {
                int j = ntile * 32 + n2 * 16 + (l4 << 2) + r;
                br[n2][r]  = Bi[j] + Bh[j];
                bz[n2][r]  = Bi[HID + j] + Bh[HID + j];
                bni[n2][r] = Bi[2 * HID + j];
                bnh[n2][r] = Bh[2 * HID + j];
            }
    } else {
        #pragma unroll
        for (int n2 = 0; n2 < 2; ++n2)
            #pragma unroll
            for (int r = 0; r < 4; ++r)
                br[n2][r] = bz[n2][r] = bni[n2][r] = bnh[n2][r] = 0.f;
    }

    float hold[2][4] = {{0,0,0,0},{0,0,0,0}};
    f32x4 acc_i[6], acc_h[6];
    #pragma unroll
    for (int f = 0; f < 6; ++f) {
        acc_i[f] = (f32x4){0.f,0.f,0.f,0.f};
        acc_h[f] = (f32x4){0.f,0.f,0.f,0.f};
    }

    f32x4 xs[4][2];                            // x stash for step s+1 (L0)

    auto do_window = [&]() {
        #pragma unroll
        for (int f = 0; f < 6; ++f) acc_i[f] = (f32x4){0.f,0.f,0.f,0.f};
        #pragma unroll
        for (int kk = 0; kk < 4; ++kk) {
            union { unsigned u[4]; bf16x8 v; } hi, lo;
            splitPack2(xs[kk][0][0], xs[kk][0][1], hi.u[0], lo.u[0]);
            splitPack2(xs[kk][0][2], xs[kk][0][3], hi.u[1], lo.u[1]);
            splitPack2(xs[kk][1][0], xs[kk][1][1], hi.u[2], lo.u[2]);
            splitPack2(xs[kk][1][2], xs[kk][1][3], hi.u[3], lo.u[3]);
            #pragma unroll
            for (int f = 0; f < 6; ++f) {
                acc_i[f] = __builtin_amdgcn_mfma_f32_16x16x32_bf16(wiR[kk][f], lo.v, acc_i[f], 0, 0, 0);
                acc_i[f] = __builtin_amdgcn_mfma_f32_16x16x32_bf16(wiR[kk][f], hi.v, acc_i[f], 0, 0, 0);
            }
        }
    };

    // ---- prologue: x-GEMM for step 0 (L0) ----
    if (layer == 0) {
        #pragma unroll
        for (int kk = 0; kk < 4; ++kk) {
            const int m = mtile * 16 + l15;
            const int k = ((kq << 2) + kk) * 32 + (l4 << 3);
            const float* xp = x + ((size_t)m * TS + 0) * HID + k;
            ld16_issue(xs[kk][0], xp);
            ld16_issue(xs[kk][1], xp + 4);
        }
        wait_vm0();
        do_window();
    }

    int w3 = 0;                                // s % 3
    for (int s = 0; s <= TS; ++s) {
        const int r3  = (w3 == 0) ? 2 : (w3 - 1);   // (s-1) % 3  (h0 read slot)
        const int wp2 = s & 1, rp2 = wp2 ^ 1;       // h1 2-buffer (L1 only)
        const bool active = layer ? (s >= 1) : (s < TS);
        const bool window = (layer == 0) && (s + 1 < TS);
        if (active) {
            #pragma unroll
            for (int f = 0; f < 6; ++f) {
                acc_h[f] = (f32x4){0.f,0.f,0.f,0.f};
                if (layer) acc_i[f] = (f32x4){0.f,0.f,0.f,0.f};
            }

            const unsigned short* pIhi = h0hi[r3];
            const unsigned short* pHhi = layer ? h1hi[rp2] : h0hi[r3];

            // ---- batched issue: 1-term h loads (+ x stash) ----
            bf16x8 hH[4], hI[4];
            #pragma unroll
            for (int kk = 0; kk < 4; ++kk) {
                const int fo = (((mtile * 16 + (kq << 2) + kk) * 64) + lane) * 8;
                ld_agent16_issue(hH[kk], pHhi + fo);
                if (layer) ld_agent16_issue(hI[kk], pIhi + fo);
            }
            if (window) {
                #pragma unroll
                for (int kk = 0; kk < 4; ++kk) {
                    const int m = mtile * 16 + l15;
                    const int k = ((kq << 2) + kk) * 32 + (l4 << 3);
                    const float* xp = x + ((size_t)m * TS + (s + 1)) * HID + k;
                    ld16_issue(xs[kk][0], xp);
                    ld16_issue(xs[kk][1], xp + 4);
                }
            }
            wait_vm0();

            // ---- MFMAs (1-term h) ----
            #pragma unroll
            for (int kk = 0; kk < 4; ++kk) {
                if (layer) {
                    #pragma unroll
                    for (int f = 0; f < 6; ++f)
                        acc_i[f] = __builtin_amdgcn_mfma_f32_16x16x32_bf16(wiR[kk][f], hI[kk], acc_i[f], 0, 0, 0);
                }
                #pragma unroll
                for (int f = 0; f < 6; ++f)
                    acc_h[f] = __builtin_amdgcn_mfma_f32_16x16x32_bf16(whR[kk][f], hH[kk], acc_h[f], 0, 0, 0);
            }

            // ---- k-split reduction ----
            if (kq != 0) {
                float* p = &ldsRed[kq - 1][lane][0];
                #pragma unroll
                for (int f = 0; f < 6; ++f) {
                    *(f32x4*)(p + f * 4)      = acc_i[f];
                    *(f32x4*)(p + 24 + f * 4) = acc_h[f];
                }
            }
            __syncthreads();                   // (A)
            if (kq == 0) {
                #pragma unroll
                for (int q = 0; q < 3; ++q) {
                    const float* p = &ldsRed[q][lane][0];
                    #pragma unroll
                    for (int f = 0; f < 6; ++f) {
                        acc_i[f] += *(const f32x4*)(p + f * 4);
                        acc_h[f] += *(const f32x4*)(p + 24 + f * 4);
                    }
                }
                // ---- gates (fp32) + fragment-layout 1-term store ----
                unsigned short* dsthi = layer ? h1hi[wp2] : h0hi[w3];
                #pragma unroll
                for (int n2 = 0; n2 < 2; ++n2) {
                    u16x4 shi; f32x4 hv;
                    #pragma unroll
                    for (int r = 0; r < 4; ++r) {
                        float vr = acc_i[n2][r]     + acc_h[n2][r]     + br[n2][r];
                        float vz = acc_i[2 + n2][r] + acc_h[2 + n2][r] + bz[n2][r];
                        float rg = sigm(vr);
                        float zg = sigm(vz);
                        float ng = tanh_(acc_i[4 + n2][r] + bni[n2][r] + rg * (acc_h[4 + n2][r] + bnh[n2][r]));
                        float h  = (1.0f - zg) * ng + zg * hold[n2][r];
                        hold[n2][r] = h;
                        hv[r] = h;
                        shi[r] = f2bf(h);
                    }
                    const int eo = (((mtile * 16 + ntile) * 64) + l15 + (n2 * 2 + (l4 >> 1)) * 16) * 8
                                 + (l4 & 1) * 4;
                    st_agent8(dsthi + eo, __builtin_bit_cast(unsigned long long, shi));
                    if (layer && s == TS) {
                        const int m = mtile * 16 + l15;
                        st_agent16(h1f + (size_t)m * HID + ntile * 32 + n2 * 16 + (l4 << 2), hv);
                    }
                }
            }
        }

        // ---- arrive: drain stores (ACKed at MALL), publish seq ----
        if (tid == 0) {
            asm volatile("s_waitcnt vmcnt(0)" ::: "memory");
            __hip_atomic_store(&seqA[gidx], (unsigned)(s + 1),
                               __ATOMIC_RELAXED, __HIP_MEMORY_SCOPE_AGENT);
        }

        // ---- barrier window: L0 computes next step's x-GEMM (reg-only) ----
        if (window) do_window();

        // ---- poll (layer-decoupled targets) ----
        // L0 wg: L0 slots (lanes 0-3) >= s+1, L1 slots (lanes 4-7) >= s.
        // L1 wg: all slots >= s+1.
        if (kq == 0) {
            const unsigned tgtStrict = (unsigned)(s + 1);
            const unsigned tgtMine   = (layer == 0 && (lane & 7) >= 4)
                                       ? (unsigned)s : tgtStrict;
            const int paddr = lane << 9;       // probe: 64 lanes -> bank 0
            for (;;) {
                unsigned probe;
                asm volatile("ds_read_b32 %0, %1\n\ts_waitcnt lgkmcnt(0)"
                             : "=v"(probe) : "v"(paddr));
                bool ok = true;
                if (lane < 8) {
                    const unsigned long long* sp =
                        (const unsigned long long*)(seqA + ((lane & 7) << 2));
                    unsigned long long a = __hip_atomic_load(sp,     __ATOMIC_RELAXED, __HIP_MEMORY_SCOPE_AGENT);
                    unsigned long long b = __hip_atomic_load(sp + 1, __ATOMIC_RELAXED, __HIP_MEMORY_SCOPE_AGENT);
                    ok = ((unsigned)a >= tgtMine) && ((unsigned)(a >> 32) >= tgtMine) &&
                         ((unsigned)b >= tgtMine) && ((unsigned)(b >> 32) >= tgtMine);
                }
                if (__all(ok)) break;
                __builtin_amdgcn_s_sleep(1);
            }
        }
        __syncthreads();                       // (B)

        w3 = (w3 == 2) ? 0 : (w3 + 1);
    }

    // ---- global fin barrier (one-shot), then FC epilogue ----
    if (tid == 0) {
        asm volatile("s_waitcnt vmcnt(0)" ::: "memory");
        __hip_atomic_fetch_add(fin, 1u, __ATOMIC_RELAXED, __HIP_MEMORY_SCOPE_AGENT);
    }
    if (wgid < 64) {
        float* fw = &ldsRed[0][0][0];             // 8 rows x 516 floats
        const float* src = fcw + (size_t)wgid * 8 * HID;
        for (int i = tid; i < (8 * HID) / 4; i += WGT) {
            f32x4 v = *(const f32x4*)(src + i * 4);
            int row = (i * 4) >> 9;
            int kk  = (i * 4) & 511;
            *(f32x4*)(fw + row * 516 + kk) = v;
        }
        if (tid == 0) {
            while (__hip_atomic_load(fin, __ATOMIC_RELAXED, __HIP_MEMORY_SCOPE_AGENT) < (unsigned)NWG)
                __builtin_amdgcn_s_sleep(1);
        }
        __syncthreads();
        const int col = wgid * 8 + (tid & 7);
        const int m0  = tid >> 3;
        float a0 = fcb[col], a1 = a0, a2 = a0, a3 = a0;
        const float* fwr = fw + (tid & 7) * 516;
        for (int k = 0; k < HID; k += 4) {
            f32x4 wv  = *(const f32x4*)(fwr + k);
            f32x4 h0v = ld_coh16f(h1f + (size_t)(m0)      * HID + k);
            f32x4 h1v = ld_coh16f(h1f + (size_t)(m0 + 32) * HID + k);
            f32x4 h2v = ld_coh16f(h1f + (size_t)(m0 + 64) * HID + k);
            f32x4 h3v = ld_coh16f(h1f + (size_t)(m0 + 96) * HID + k);
            a0 += h0v[0]*wv[0] + h0v[1]*wv[1] + h0v[2]*wv[2] + h0v[3]*wv[3];
            a1 += h1v[0]*wv[0] + h1v[1]*wv[1] + h1v[2]*wv[2] + h1v[3]*wv[3];
            a2 += h2v[0]*wv[0] + h2v[1]*wv[1] + h2v[2]*wv[2] + h2v[3]*wv[3];
            a3 += h3v[0]*wv[0] + h3v[1]*wv[1] + h3v[2]*wv[2] + h3v[3]*wv[3];
        }
        out[(size_t)(m0)      * HID + col] = a0;
        out[(size_t)(m0 + 32) * HID + col] = a1;
        out[(size_t)(m0 + 64) * HID + col] = a2;
        out[(size_t)(m0 + 96) * HID + col] = a3;
    }
}

extern "C" void kernel_launch(void* const* d_in, const int* in_sizes, int n_in,
                              void* d_out, int out_size, void* d_ws, size_t ws_size,
                              hipStream_t stream) {
    (void)in_sizes; (void)n_in; (void)out_size; (void)ws_size;
    hipMemsetAsync(d_ws, 0, WS_ZERO, stream);
    gru_persistent<<<dim3(NWG), dim3(WGT), 0, stream>>>(
        (const float*)d_in[0],
        (const float*)d_in[1], (const float*)d_in[2],
        (const float*)d_in[3], (const float*)d_in[4],
        (const float*)d_in[5], (const float*)d_in[6],
        (const float*)d_in[7], (const float*)d_in[8],
        (const float*)d_in[9], (const float*)d_in[10],
        (float*)d_out, (unsigned char*)d_ws);
}

// Round 16
// 7230.299 us; speedup vs baseline: 1.0250x; 1.0250x over previous
//
#include <hip/hip_runtime.h>

// ---------------------------------------------------------------------------
// Persistent 2-layer GRU, MI355X (gfx950).  B=128, T=1024, D=H=512.
// R14-proven base (256 wgs x 256 thr, (layer, mtile, ntile) = 16 rows x
// 32 cols, k-split 4x128, weights in registers, 1-TERM bf16 h exchange via
// agent-scope (sc1) MALL ops, per-wg seq words, strict per-mtile barrier,
// vmcnt(0)-only waits). R15's layer-decoupling reverted (measured flat).
// CHANGES vs R14:
//  1. Poll probe removed (served its purpose; ~0.1-0.25us/interval saved).
//  2. Gate tail parallelized 2x: ALL 4 waves write k-split partials to LDS
//     [4][64][49]; wave 0 reduces+gates+stores n2=0, wave 1 n2=1. Each gate
//     wave drains its own stores; __syncthreads() makes both drains block-
//     wide; then tid0 publishes.
// ---------------------------------------------------------------------------

#define TS   1024
#define HID  512
#define NWG  256
#define WGT  256

typedef __attribute__((ext_vector_type(8))) short bf16x8;
typedef __attribute__((ext_vector_type(4))) unsigned short u16x4;
typedef __attribute__((ext_vector_type(4))) float f32x4;

#define WS_FIN      2048
#define WS_HBUF     8192
#define HBUF_ELEMS  65536                             // 128*512 bf16 per buffer
#define WS_H1F      (WS_HBUF + 8 * HBUF_ELEMS * 2)    // fp32 [128][512]
#define WS_ZERO     (WS_HBUF + 8 * HBUF_ELEMS * 2)

__device__ __forceinline__ unsigned short f2bf(float f) {
    unsigned u = __float_as_uint(f);
    u += 0x7FFFu + ((u >> 16) & 1u);
    return (unsigned short)(u >> 16);
}
__device__ __forceinline__ float bf2f(unsigned short s) {
    return __uint_as_float(((unsigned)s) << 16);
}
__device__ __forceinline__ float sigm(float v) { return 1.0f / (1.0f + __expf(-v)); }
__device__ __forceinline__ float tanh_(float v) { return 1.0f - 2.0f / (1.0f + __expf(2.0f * v)); }

// agent-scope (MALL) ops
__device__ __forceinline__ void st_agent8(void* p, unsigned long long v) {
    asm volatile("global_store_dwordx2 %0, %1, off sc1" :: "v"(p), "v"(v) : "memory");
}
__device__ __forceinline__ void st_agent16(void* p, f32x4 v) {
    asm volatile("global_store_dwordx4 %0, %1, off sc1" :: "v"(p), "v"(v) : "memory");
}
__device__ __forceinline__ void ld_agent16_issue(bf16x8& d, const unsigned short* p) {
    asm volatile("global_load_dwordx4 %0, %1, off sc1" : "=v"(d) : "v"(p));
}
// plain cached load (x input), issue-only
__device__ __forceinline__ void ld16_issue(f32x4& d, const float* p) {
    asm volatile("global_load_dwordx4 %0, %1, off" : "=v"(d) : "v"(p));
}
__device__ __forceinline__ void wait_vm0() {
    asm volatile("s_waitcnt vmcnt(0)" ::: "memory");
    __builtin_amdgcn_sched_barrier(0);
}
// coherent fp32x4 load (FC epilogue only)
__device__ __forceinline__ f32x4 ld_coh16f(const float* p) {
    const unsigned long long* q = (const unsigned long long*)p;
    union { unsigned long long u[2]; f32x4 v; } r;
    r.u[0] = __hip_atomic_load(q,     __ATOMIC_RELAXED, __HIP_MEMORY_SCOPE_AGENT);
    r.u[1] = __hip_atomic_load(q + 1, __ATOMIC_RELAXED, __HIP_MEMORY_SCOPE_AGENT);
    return r.v;
}
__device__ __forceinline__ void splitPack2(float a, float b, unsigned& hiw, unsigned& low) {
    unsigned ba = __float_as_uint(a), bb = __float_as_uint(b);
    unsigned ha = ba & 0xFFFF0000u,   hb = bb & 0xFFFF0000u;
    float la = a - __uint_as_float(ha);
    float lb = b - __uint_as_float(hb);
    hiw = (ba >> 16) | hb;
    low = (__float_as_uint(la) >> 16) | (__float_as_uint(lb) & 0xFFFF0000u);
}

__global__ void __launch_bounds__(WGT, 1)
gru_persistent(const float* __restrict__ x,
               const float* __restrict__ wi0, const float* __restrict__ wh0,
               const float* __restrict__ bi0, const float* __restrict__ bh0,
               const float* __restrict__ wi1, const float* __restrict__ wh1,
               const float* __restrict__ bi1, const float* __restrict__ bh1,
               const float* __restrict__ fcw, const float* __restrict__ fcb,
               float* __restrict__ out, unsigned char* __restrict__ ws)
{
    __shared__ float ldsRed[4][64][49];        // 50176 B k-split partials (all 4 waves)

    const int tid   = threadIdx.x;
    const int lane  = tid & 63;
    const int kq    = tid >> 6;                // wave id = k-quarter
    const int wgid  = blockIdx.x;
    const int layer = wgid >> 7;
    const int wid   = wgid & 127;
    const int mtile = wid & 7;                 // 16-row m-tile (barrier group)
    const int ntile = wid >> 3;                // 32-col hidden tile
    const int l15   = lane & 15;
    const int l4    = lane >> 4;
    const int gidx  = layer * 16 + ntile;      // 0..31 within mtile-group

    unsigned* seqA = (unsigned*)(ws + (size_t)mtile * 256);
    unsigned* fin  = (unsigned*)(ws + WS_FIN);
    unsigned short* hbm = (unsigned short*)(ws + WS_HBUF);
    float* h1f = (float*)(ws + WS_H1F);

    // 1-term h: hi buffers only
    unsigned short* h0hi[2] = { hbm + 0 * HBUF_ELEMS, hbm + 1 * HBUF_ELEMS };
    unsigned short* h1hi[2] = { hbm + 4 * HBUF_ELEMS, hbm + 5 * HBUF_ELEMS };

    // ---- stage weight fragments into REGISTERS (fp32 -> bf16) ----
    bf16x8 wiR[4][6], whR[4][6];
    {
        const float* Wi = layer ? wi1 : wi0;
        const float* Wh = layer ? wh1 : wh0;
        #pragma unroll
        for (int kk = 0; kk < 4; ++kk) {
            const int kc = (kq << 2) + kk;
            #pragma unroll
            for (int f = 0; f < 6; ++f) {
                const int g = f >> 1, n2 = f & 1;
                const int jg = g * HID + ntile * 32 + n2 * 16 + l15;
                const float* pi = Wi + (size_t)jg * HID + kc * 32 + (l4 << 3);
                const float* ph = Wh + (size_t)jg * HID + kc * 32 + (l4 << 3);
                #pragma unroll
                for (int e = 0; e < 8; ++e) {
                    wiR[kk][f][e] = (short)f2bf(pi[e]);
                    whR[kk][f][e] = (short)f2bf(ph[e]);
                }
            }
        }
    }

    // ---- per-thread biases: waves 0 and 1 each own n2 = kq ----
    const bool gateWave = (kq < 2);
    float br[4], bz[4], bni[4], bnh[4];
    if (gateWave) {
        const float* Bi = layer ? bi1 : bi0;
        const float* Bh = layer ? bh1 : bh0;
        #pragma unroll
        for (int r = 0; r < 4; ++r) {
            int j = ntile * 32 + kq * 16 + (l4 << 2) + r;
            br[r]  = Bi[j] + Bh[j];
            bz[r]  = Bi[HID + j] + Bh[HID + j];
            bni[r] = Bi[2 * HID + j];
            bnh[r] = Bh[2 * HID + j];
        }
    } else {
        #pragma unroll
        for (int r = 0; r < 4; ++r) br[r] = bz[r] = bni[r] = bnh[r] = 0.f;
    }

    float hold[4] = {0,0,0,0};                 // per gate-wave: its n2 slice
    f32x4 acc_i[6], acc_h[6];
    #pragma unroll
    for (int f = 0; f < 6; ++f) {
        acc_i[f] = (f32x4){0.f,0.f,0.f,0.f};
        acc_h[f] = (f32x4){0.f,0.f,0.f,0.f};
    }

    f32x4 xs[4][2];                            // x stash for step s+1 (L0)

    auto do_window = [&]() {
        #pragma unroll
        for (int f = 0; f < 6; ++f) acc_i[f] = (f32x4){0.f,0.f,0.f,0.f};
        #pragma unroll
        for (int kk = 0; kk < 4; ++kk) {
            union { unsigned u[4]; bf16x8 v; } hi, lo;
            splitPack2(xs[kk][0][0], xs[kk][0][1], hi.u[0], lo.u[0]);
            splitPack2(xs[kk][0][2], xs[kk][0][3], hi.u[1], lo.u[1]);
            splitPack2(xs[kk][1][0], xs[kk][1][1], hi.u[2], lo.u[2]);
            splitPack2(xs[kk][1][2], xs[kk][1][3], hi.u[3], lo.u[3]);
            #pragma unroll
            for (int f = 0; f < 6; ++f) {
                acc_i[f] = __builtin_amdgcn_mfma_f32_16x16x32_bf16(wiR[kk][f], lo.v, acc_i[f], 0, 0, 0);
                acc_i[f] = __builtin_amdgcn_mfma_f32_16x16x32_bf16(wiR[kk][f], hi.v, acc_i[f], 0, 0, 0);
            }
        }
    };

    // ---- prologue: x-GEMM for step 0 (L0) ----
    if (layer == 0) {
        #pragma unroll
        for (int kk = 0; kk < 4; ++kk) {
            const int m = mtile * 16 + l15;
            const int k = ((kq << 2) + kk) * 32 + (l4 << 3);
            const float* xp = x + ((size_t)m * TS + 0) * HID + k;
            ld16_issue(xs[kk][0], xp);
            ld16_issue(xs[kk][1], xp + 4);
        }
        wait_vm0();
        do_window();
    }

    for (int s = 0; s <= TS; ++s) {
        const int wp = s & 1, rp = wp ^ 1;
        const bool active = layer ? (s >= 1) : (s < TS);
        const bool window = (layer == 0) && (s + 1 < TS);
        if (active) {
            #pragma unroll
            for (int f = 0; f < 6; ++f) {
                acc_h[f] = (f32x4){0.f,0.f,0.f,0.f};
                if (layer) acc_i[f] = (f32x4){0.f,0.f,0.f,0.f};
            }

            const unsigned short* pIhi = h0hi[rp];
            const unsigned short* pHhi = layer ? h1hi[rp] : h0hi[rp];

            // ---- batched issue: 1-term h loads (+ x stash) ----
            bf16x8 hH[4], hI[4];
            #pragma unroll
            for (int kk = 0; kk < 4; ++kk) {
                const int fo = (((mtile * 16 + (kq << 2) + kk) * 64) + lane) * 8;
                ld_agent16_issue(hH[kk], pHhi + fo);
                if (layer) ld_agent16_issue(hI[kk], pIhi + fo);
            }
            if (window) {
                #pragma unroll
                for (int kk = 0; kk < 4; ++kk) {
                    const int m = mtile * 16 + l15;
                    const int k = ((kq << 2) + kk) * 32 + (l4 << 3);
                    const float* xp = x + ((size_t)m * TS + (s + 1)) * HID + k;
                    ld16_issue(xs[kk][0], xp);
                    ld16_issue(xs[kk][1], xp + 4);
                }
            }
            wait_vm0();

            // ---- MFMAs (1-term h) ----
            #pragma unroll
            for (int kk = 0; kk < 4; ++kk) {
                if (layer) {
                    #pragma unroll
                    for (int f = 0; f < 6; ++f)
                        acc_i[f] = __builtin_amdgcn_mfma_f32_16x16x32_bf16(wiR[kk][f], hI[kk], acc_i[f], 0, 0, 0);
                }
                #pragma unroll
                for (int f = 0; f < 6; ++f)
                    acc_h[f] = __builtin_amdgcn_mfma_f32_16x16x32_bf16(whR[kk][f], hH[kk], acc_h[f], 0, 0, 0);
            }

            // ---- k-split partials: ALL 4 waves -> LDS ----
            {
                float* p = &ldsRed[kq][lane][0];
                #pragma unroll
                for (int f = 0; f < 6; ++f) {
                    *(f32x4*)(p + f * 4)      = acc_i[f];
                    *(f32x4*)(p + 24 + f * 4) = acc_h[f];
                }
            }
            __syncthreads();                   // (A)

            // ---- reduce+gates+store: wave w handles n2 = w (w in {0,1}) ----
            if (gateWave) {
                f32x4 ai0 = {0,0,0,0}, ai1 = {0,0,0,0}, ai2 = {0,0,0,0};
                f32x4 ah0 = {0,0,0,0}, ah1 = {0,0,0,0}, ah2 = {0,0,0,0};
                #pragma unroll
                for (int q = 0; q < 4; ++q) {
                    const float* p = &ldsRed[q][lane][0];
                    ai0 += *(const f32x4*)(p + (0 + kq) * 4);
                    ai1 += *(const f32x4*)(p + (2 + kq) * 4);
                    ai2 += *(const f32x4*)(p + (4 + kq) * 4);
                    ah0 += *(const f32x4*)(p + 24 + (0 + kq) * 4);
                    ah1 += *(const f32x4*)(p + 24 + (2 + kq) * 4);
                    ah2 += *(const f32x4*)(p + 24 + (4 + kq) * 4);
                }
                unsigned short* dsthi = layer ? h1hi[wp] : h0hi[wp];
                u16x4 shi; f32x4 hv;
                #pragma unroll
                for (int r = 0; r < 4; ++r) {
                    float vr = ai0[r] + ah0[r] + br[r];
                    float vz = ai1[r] + ah1[r] + bz[r];
                    float rg = sigm(vr);
                    float zg = sigm(vz);
                    float ng = tanh_(ai2[r] + bni[r] + rg * (ah2[r] + bnh[r]));
                    float h  = (1.0f - zg) * ng + zg * hold[r];
                    hold[r] = h;
                    hv[r] = h;
                    shi[r] = f2bf(h);
                }
                const int eo = (((mtile * 16 + ntile) * 64) + l15 + (kq * 2 + (l4 >> 1)) * 16) * 8
                             + (l4 & 1) * 4;
                st_agent8(dsthi + eo, __builtin_bit_cast(unsigned long long, shi));
                if (layer && s == TS) {
                    const int m = mtile * 16 + l15;
                    st_agent16(h1f + (size_t)m * HID + ntile * 32 + kq * 16 + (l4 << 2), hv);
                }
                asm volatile("s_waitcnt vmcnt(0)" ::: "memory");   // drain own stores
            }
            __syncthreads();                   // (A2): both gate waves drained
        }

        // ---- arrive: publish seq (stores already drained block-wide) ----
        if (tid == 0) {
            __hip_atomic_store(&seqA[gidx], (unsigned)(s + 1),
                               __ATOMIC_RELAXED, __HIP_MEMORY_SCOPE_AGENT);
        }

        // ---- barrier window: L0 computes next step's x-GEMM (reg-only) ----
        if (window) do_window();

        // ---- poll: all 32 group seqs >= s+1 ----
        if (kq == 0) {
            const unsigned tgt = (unsigned)(s + 1);
            for (;;) {
                bool ok = true;
                if (lane < 8) {
                    const unsigned long long* sp =
                        (const unsigned long long*)(seqA + ((lane & 7) << 2));
                    unsigned long long a = __hip_atomic_load(sp,     __ATOMIC_RELAXED, __HIP_MEMORY_SCOPE_AGENT);
                    unsigned long long b = __hip_atomic_load(sp + 1, __ATOMIC_RELAXED, __HIP_MEMORY_SCOPE_AGENT);
                    ok = ((unsigned)a >= tgt) && ((unsigned)(a >> 32) >= tgt) &&
                         ((unsigned)b >= tgt) && ((unsigned)(b >> 32) >= tgt);
                }
                if (__all(ok)) break;
                __builtin_amdgcn_s_sleep(1);
            }
        }
        __syncthreads();                       // (B)
    }

    // ---- global fin barrier (one-shot), then FC epilogue ----
    if (tid == 0) {
        asm volatile("s_waitcnt vmcnt(0)" ::: "memory");
        __hip_atomic_fetch_add(fin, 1u, __ATOMIC_RELAXED, __HIP_MEMORY_SCOPE_AGENT);
    }
    if (wgid < 64) {
        float* fw = &ldsRed[0][0][0];             // 8 rows x 516 floats
        const float* src = fcw + (size_t)wgid * 8 * HID;
        for (int i = tid; i < (8 * HID) / 4; i += WGT) {
            f32x4 v = *(const f32x4*)(src + i * 4);
            int row = (i * 4) >> 9;
            int kk  = (i * 4) & 511;
            *(f32x4*)(fw + row * 516 + kk) = v;
        }
        if (tid == 0) {
            while (__hip_atomic_load(fin, __ATOMIC_RELAXED, __HIP_MEMORY_SCOPE_AGENT) < (unsigned)NWG)
                __builtin_amdgcn_s_sleep(1);
        }
        __syncthreads();
        const int col = wgid * 8 + (tid & 7);
        const int m0  = tid >> 3;
        float a0 = fcb[col], a1 = a0, a2 = a0, a3 = a0;
        const float* fwr = fw + (tid & 7) * 516;
        for (int k = 0; k < HID; k += 4) {
            f32x4 wv  = *(const f32x4*)(fwr + k);
            f32x4 h0v = ld_coh16f(h1f + (size_t)(m0)      * HID + k);
            f32x4 h1v = ld_coh16f(h1f + (size_t)(m0 + 32) * HID + k);
            f32x4 h2v = ld_coh16f(h1f + (size_t)(m0 + 64) * HID + k);
            f32x4 h3v = ld_coh16f(h1f + (size_t)(m0 + 96) * HID + k);
            a0 += h0v[0]*wv[0] + h0v[1]*wv[1] + h0v[2]*wv[2] + h0v[3]*wv[3];
            a1 += h1v[0]*wv[0] + h1v[1]*wv[1] + h1v[2]*wv[2] + h1v[3]*wv[3];
            a2 += h2v[0]*wv[0] + h2v[1]*wv[1] + h2v[2]*wv[2] + h2v[3]*wv[3];
            a3 += h3v[0]*wv[0] + h3v[1]*wv[1] + h3v[2]*wv[2] + h3v[3]*wv[3];
        }
        out[(size_t)(m0)      * HID + col] = a0;
        out[(size_t)(m0 + 32) * HID + col] = a1;
        out[(size_t)(m0 + 64) * HID + col] = a2;
        out[(size_t)(m0 + 96) * HID + col] = a3;
    }
}

extern "C" void kernel_launch(void* const* d_in, const int* in_sizes, int n_in,
                              void* d_out, int out_size, void* d_ws, size_t ws_size,
                              hipStream_t stream) {
    (void)in_sizes; (void)n_in; (void)out_size; (void)ws_size;
    hipMemsetAsync(d_ws, 0, WS_ZERO, stream);
    gru_persistent<<<dim3(NWG), dim3(WGT), 0, stream>>>(
        (const float*)d_in[0],
        (const float*)d_in[1], (const float*)d_in[2],
        (const float*)d_in[3], (const float*)d_in[4],
        (const float*)d_in[5], (const float*)d_in[6],
        (const float*)d_in[7], (const float*)d_in[8],
        (const float*)d_in[9], (const float*)d_in[10],
        (float*)d_out, (unsigned char*)d_ws);
}